// Round 1
// baseline (1045.479 us; speedup 1.0000x reference)
//
#include <hip/hip_runtime.h>

typedef unsigned int uint32;
typedef __bf16 bf16x8 __attribute__((ext_vector_type(8)));
typedef float f32x4 __attribute__((ext_vector_type(4)));

constexpr int N_C = 100000, N_T = 5000, E_EDGES = 2000000;
constexpr int D_C = 1024, D_T = 1280, H = 64, H2 = 32, NL = 3;
constexpr int NBC = (N_C + 127) / 128;   // 782 MFMA blocks for compounds
constexpr int NBT = (N_T + 127) / 128;   // 40

__device__ inline unsigned short f2bf(float f) {
  uint32 u = __float_as_uint(f);
  u += 0x7fffu + ((u >> 16) & 1u);          // round-to-nearest-even
  return (unsigned short)(u >> 16);
}

// ---------------- prep: all weight transposes + zero both count arrays (1 node)
__global__ __launch_bounds__(256) void prep_kernel(
    const float* __restrict__ Wc, const float* __restrict__ Wt,
    const float* __restrict__ Wl, const float* __restrict__ Wr,
    __bf16* __restrict__ WcT, __bf16* __restrict__ WtT, __bf16* __restrict__ WsT,
    int* __restrict__ cnt_t, int* __restrict__ cnt_c)
{
  int t = blockIdx.x * 256 + threadIdx.x;
  const int Z = N_T + N_C;            // zero words
  const int A = D_C * 64;
  const int B = D_T * 64;
  const int S = 6 * 64 * 64;
  if (t < Z) {
    if (t < N_T) cnt_t[t] = 0; else cnt_c[t - N_T] = 0;
    return;
  }
  t -= Z;
  if (t < A) { int n = t & 63, k = t >> 6; WcT[(size_t)n * D_C + k] = (__bf16)Wc[(size_t)k * 64 + n]; return; }
  t -= A;
  if (t < B) { int n = t & 63, k = t >> 6; WtT[(size_t)n * D_T + k] = (__bf16)Wt[(size_t)k * 64 + n]; return; }
  t -= B;
  if (t < S) {
    int i = t >> 12;
    int r = t & 4095; int n = r & 63, k = r >> 6;
    const float* src = (i < 3) ? (Wl + (size_t)i * 4096) : (Wr + (size_t)(i - 3) * 4096);
    WsT[(size_t)i * 4096 + (size_t)n * 64 + k] = (__bf16)src[(size_t)k * 64 + n];
  }
}

// ---------------- MFMA projection body: y = relu(x @ W + b)
template<int K>
__device__ __forceinline__ void projM_body(
    const float* __restrict__ x, const __bf16* __restrict__ WT,
    const float* __restrict__ b, float* __restrict__ y,
    unsigned short* __restrict__ yh, int n, int bidx)
{
  int w = threadIdx.x >> 6, l = threadIdx.x & 63;
  int lm = l & 15, lk = l >> 4;
  int base = bidx * 128 + w * 32;
  int r0 = base + lm;      if (r0 >= n) r0 = n - 1;
  int r1 = base + 16 + lm; if (r1 >= n) r1 = n - 1;
  const float* xp0 = x + (size_t)r0 * K + lk * 8;
  const float* xp1 = x + (size_t)r1 * K + lk * 8;
  const __bf16* wp = WT + (size_t)lm * K + lk * 8;

  f32x4 acc0[4] = {{0,0,0,0},{0,0,0,0},{0,0,0,0},{0,0,0,0}};
  f32x4 acc1[4] = {{0,0,0,0},{0,0,0,0},{0,0,0,0},{0,0,0,0}};

  float4 p00 = *(const float4*)(xp0);
  float4 p01 = *(const float4*)(xp0 + 4);
  float4 p10 = *(const float4*)(xp1);
  float4 p11 = *(const float4*)(xp1 + 4);

  for (int k0 = 0; k0 < K; k0 += 32) {
    bf16x8 a0, a1;
    a0[0]=(__bf16)p00.x; a0[1]=(__bf16)p00.y; a0[2]=(__bf16)p00.z; a0[3]=(__bf16)p00.w;
    a0[4]=(__bf16)p01.x; a0[5]=(__bf16)p01.y; a0[6]=(__bf16)p01.z; a0[7]=(__bf16)p01.w;
    a1[0]=(__bf16)p10.x; a1[1]=(__bf16)p10.y; a1[2]=(__bf16)p10.z; a1[3]=(__bf16)p10.w;
    a1[4]=(__bf16)p11.x; a1[5]=(__bf16)p11.y; a1[6]=(__bf16)p11.z; a1[7]=(__bf16)p11.w;
    if (k0 + 32 < K) {
      p00 = *(const float4*)(xp0 + k0 + 32);
      p01 = *(const float4*)(xp0 + k0 + 36);
      p10 = *(const float4*)(xp1 + k0 + 32);
      p11 = *(const float4*)(xp1 + k0 + 36);
    }
#pragma unroll
    for (int fn = 0; fn < 4; ++fn) {
      bf16x8 bv = *(const bf16x8*)(wp + (size_t)fn * 16 * K + k0);
      acc0[fn] = __builtin_amdgcn_mfma_f32_16x16x32_bf16(a0, bv, acc0[fn], 0, 0, 0);
      acc1[fn] = __builtin_amdgcn_mfma_f32_16x16x32_bf16(a1, bv, acc1[fn], 0, 0, 0);
    }
  }

#pragma unroll
  for (int fn = 0; fn < 4; ++fn) {
    int col = fn * 16 + lm;
    float bb = b[col];
#pragma unroll
    for (int reg = 0; reg < 4; ++reg) {
      int row = base + lk * 4 + reg;
      if (row < n) {
        float o = fmaxf(acc0[fn][reg] + bb, 0.f);
        y[(size_t)row * 64 + col] = o;
        yh[(size_t)row * 64 + col] = f2bf(o);
      }
      row = base + 16 + lk * 4 + reg;
      if (row < n) {
        float o = fmaxf(acc1[fn][reg] + bb, 0.f);
        y[(size_t)row * 64 + col] = o;
        yh[(size_t)row * 64 + col] = f2bf(o);
      }
    }
  }
}

__global__ __launch_bounds__(256) void proj_kernel(
    const float* __restrict__ x_comp, const __bf16* __restrict__ WcT,
    const float* __restrict__ bc, float* __restrict__ xc, unsigned short* __restrict__ xch,
    const float* __restrict__ x_tgt, const __bf16* __restrict__ WtT,
    const float* __restrict__ bt, float* __restrict__ xt, unsigned short* __restrict__ xth)
{
  if (blockIdx.x < NBC) projM_body<D_C>(x_comp, WcT, bc, xc, xch, N_C, blockIdx.x);
  else                  projM_body<D_T>(x_tgt, WtT, bt, xt, xth, N_T, blockIdx.x - NBC);
}

// ---------------- merged histograms (1 node)
__global__ __launch_bounds__(256) void hist_kernel(
    const int* __restrict__ dst_ct, int* __restrict__ cnt_t,
    const int* __restrict__ dst_tc, int* __restrict__ cnt_c)
{
  __shared__ int sh[N_T];
  if (blockIdx.x < 128) {
    for (int i = threadIdx.x; i < N_T; i += 256) sh[i] = 0;
    __syncthreads();
    int stride = 128 * 256;
    for (int e = blockIdx.x * 256 + threadIdx.x; e < E_EDGES; e += stride)
      atomicAdd(&sh[dst_ct[e]], 1);
    __syncthreads();
    for (int i = threadIdx.x; i < N_T; i += 256) {
      int v = sh[i];
      if (v) atomicAdd(&cnt_t[i], v);
    }
  } else {
    int bid = blockIdx.x - 128;
    int stride = 2048 * 256;
    for (int e = bid * 256 + threadIdx.x; e < E_EDGES; e += stride)
      atomicAdd(&cnt_c[dst_tc[e]], 1);
  }
}

// ---------------- scanA: per-chunk scan of cnt_c (98 blocks) + full scan of cnt_t (1 block)
__global__ __launch_bounds__(256) void scanA_kernel(
    const int* __restrict__ cnt_c, int* __restrict__ rowptr_c, int* __restrict__ bsum,
    const int* __restrict__ cnt_t, int* __restrict__ rowptr_t, int* __restrict__ fillptr_t)
{
  __shared__ int sh[256];
  int tid = threadIdx.x;
  if (blockIdx.x < 98) {
    int bid = blockIdx.x;
    int base = bid * 1024 + tid * 4;
    int v0 = (base + 0 < N_C) ? cnt_c[base + 0] : 0;
    int v1 = (base + 1 < N_C) ? cnt_c[base + 1] : 0;
    int v2 = (base + 2 < N_C) ? cnt_c[base + 2] : 0;
    int v3 = (base + 3 < N_C) ? cnt_c[base + 3] : 0;
    int t = v0 + v1 + v2 + v3;
    sh[tid] = t;
    __syncthreads();
    for (int off = 1; off < 256; off <<= 1) {
      int xv = (tid >= off) ? sh[tid - off] : 0;
      __syncthreads();
      sh[tid] += xv;
      __syncthreads();
    }
    int incl = sh[tid];
    int excl = incl - t;
    if (base + 0 < N_C) rowptr_c[base + 0] = excl;
    if (base + 1 < N_C) rowptr_c[base + 1] = excl + v0;
    if (base + 2 < N_C) rowptr_c[base + 2] = excl + v0 + v1;
    if (base + 3 < N_C) rowptr_c[base + 3] = excl + v0 + v1 + v2;
    if (tid == 255) bsum[bid] = incl;
  } else {
    // single-block full exclusive scan of cnt_t (5000 entries)
    const int CH = 20;
    int base = tid * CH;
    int loc[CH]; int s = 0;
#pragma unroll
    for (int i = 0; i < CH; ++i) {
      int idx = base + i;
      int v = (idx < N_T) ? cnt_t[idx] : 0;
      loc[i] = v; s += v;
    }
    sh[tid] = s;
    __syncthreads();
    for (int off = 1; off < 256; off <<= 1) {
      int xv = (tid >= off) ? sh[tid - off] : 0;
      __syncthreads();
      sh[tid] += xv;
      __syncthreads();
    }
    int run = sh[tid] - s;
#pragma unroll
    for (int i = 0; i < CH; ++i) {
      int idx = base + i;
      if (idx < N_T) { rowptr_t[idx] = run; fillptr_t[idx] = run; }
      run += loc[i];
    }
    if (tid == 255) rowptr_t[N_T] = E_EDGES;
  }
}

// ---------------- scanB: every block redundantly scans the 98 block sums, applies its chunk
__global__ __launch_bounds__(256) void scanB_kernel(
    const int* __restrict__ bsum, int* __restrict__ rowptr_c, int* __restrict__ fillptr_c)
{
  __shared__ int sh[128];
  int tid = threadIdx.x;
  if (tid < 128) sh[tid] = (tid < 98) ? bsum[tid] : 0;
  __syncthreads();
  for (int off = 1; off < 128; off <<= 1) {
    int xv = (tid < 128 && tid >= off) ? sh[tid - off] : 0;
    __syncthreads();
    if (tid < 128) sh[tid] += xv;
    __syncthreads();
  }
  int bofs = (blockIdx.x > 0) ? sh[blockIdx.x - 1] : 0;
  int base = blockIdx.x * 1024 + tid * 4;
#pragma unroll
  for (int i = 0; i < 4; ++i) {
    int idx = base + i;
    if (idx < N_C) {
      int v = rowptr_c[idx] + bofs;
      rowptr_c[idx] = v;
      fillptr_c[idx] = v;
    }
  }
  if (blockIdx.x == 97 && tid == 255) rowptr_c[N_C] = E_EDGES;
}

// ---------------- merged CSR fill (1 node)
__global__ __launch_bounds__(256) void fill_kernel(
    const int* __restrict__ src_ct, const int* __restrict__ dst_ct,
    int* __restrict__ fillptr_t, int* __restrict__ col_ct,
    const int* __restrict__ src_tc, const int* __restrict__ dst_tc,
    int* __restrict__ fillptr_c, int* __restrict__ col_tc)
{
  const int* src; const int* dst; int* fp; int* col; int bid;
  if (blockIdx.x < 2048) { src = src_ct; dst = dst_ct; fp = fillptr_t; col = col_ct; bid = blockIdx.x; }
  else                   { src = src_tc; dst = dst_tc; fp = fillptr_c; col = col_tc; bid = blockIdx.x - 2048; }
  int stride = 2048 * 256;
  for (int e = bid * 256 + threadIdx.x; e < E_EDGES; e += stride) {
    int p = atomicAdd(&fp[dst[e]], 1);
    col[p] = src[e];
  }
}

// ---------------- one node per layer: target SAGE (blocks [0,N_T)) + fused compound agg+MFMA
__global__ __launch_bounds__(256) void layer_kernel(
    // target side
    const unsigned short* __restrict__ xch_a, const float* __restrict__ xt_a,
    const int* __restrict__ rowptr_t, const int* __restrict__ col_ct,
    const float* __restrict__ Wl_t, const float* __restrict__ bl_t, const float* __restrict__ Wr_t,
    float* __restrict__ xt_n, unsigned short* __restrict__ xth_n,
    // compound side
    const unsigned short* __restrict__ xth_a, const int* __restrict__ rowptr_c,
    const int* __restrict__ col_tc,
    const __bf16* __restrict__ WlT, const __bf16* __restrict__ WrT,
    const float* __restrict__ bl_c, const float* __restrict__ xc_a,
    float* __restrict__ xc_n, unsigned short* __restrict__ xch_n)
{
  __shared__ __align__(16) uint32 meanp[128][36];   // packed bf16 pairs, padded row
  __shared__ __align__(16) float part[4][64];
  __shared__ __align__(16) float opart[4][64];

  int l = threadIdx.x & 63, w = threadIdx.x >> 6;
  int d = l & 31, half = l >> 5;

  if (blockIdx.x < N_T) {
    // -------- target-side SAGE: one block per row; wave quarters, lane-halves by edge parity
    int r = blockIdx.x;
    int start = rowptr_t[r], end = rowptr_t[r + 1];
    int deg = end - start;
    int quarter = (deg + 3) >> 2;
    int js = start + w * quarter;
    int je = js + quarter; if (je > end) je = end;
    const uint32* xp = (const uint32*)xch_a;
    float a0 = 0.f, a1 = 0.f;
    int j = js + half;
    for (; j + 6 < je; j += 8) {
      int c0 = col_ct[j], c1 = col_ct[j + 2], c2 = col_ct[j + 4], c3 = col_ct[j + 6];
      uint32 v0 = xp[(size_t)c0 * 32 + d];
      uint32 v1 = xp[(size_t)c1 * 32 + d];
      uint32 v2 = xp[(size_t)c2 * 32 + d];
      uint32 v3 = xp[(size_t)c3 * 32 + d];
      a0 += __uint_as_float(v0 << 16); a1 += __uint_as_float(v0 & 0xffff0000u);
      a0 += __uint_as_float(v1 << 16); a1 += __uint_as_float(v1 & 0xffff0000u);
      a0 += __uint_as_float(v2 << 16); a1 += __uint_as_float(v2 & 0xffff0000u);
      a0 += __uint_as_float(v3 << 16); a1 += __uint_as_float(v3 & 0xffff0000u);
    }
    for (; j < je; j += 2) {
      uint32 v = xp[(size_t)col_ct[j] * 32 + d];
      a0 += __uint_as_float(v << 16); a1 += __uint_as_float(v & 0xffff0000u);
    }
    a0 += __shfl_xor(a0, 32, 64);
    a1 += __shfl_xor(a1, 32, 64);
    if (half == 0) *(float2*)&part[w][2 * d] = make_float2(a0, a1);
    __syncthreads();
    float m = (part[0][l] + part[1][l] + part[2][l] + part[3][l])
              * ((deg > 0) ? (1.0f / (float)deg) : 0.f);
    float xv = xt_a[(size_t)r * 64 + l];
    float o = 0.f;
    int k0 = w * 16;
#pragma unroll
    for (int kk = 0; kk < 16; ++kk) {
      int k = k0 + kk;
      float mk = __uint_as_float(__builtin_amdgcn_readlane(__float_as_uint(m), k));
      float xk = __uint_as_float(__builtin_amdgcn_readlane(__float_as_uint(xv), k));
      o = fmaf(mk, Wl_t[k * 64 + l], o);
      o = fmaf(xk, Wr_t[k * 64 + l], o);
    }
    opart[w][l] = o;
    __syncthreads();
    if (w == 0) {
      float oo = opart[0][l] + opart[1][l] + opart[2][l] + opart[3][l] + bl_t[l];
      float res = fmaxf(oo, 0.f) + xv;
      xt_n[(size_t)r * 64 + l] = res;
      xth_n[(size_t)r * 64 + l] = f2bf(res);
    }
    return;
  }

  // -------- compound side: aggregate 32 rows/wave into LDS, then MFMA combine
  int bblk = blockIdx.x - N_T;
  int bbase = bblk * 128;

  // preload this wave's 33 rowptr values into a register, shfl per round
  int rp_idx = bbase + w * 32 + ((l <= 32) ? l : 32);
  if (rp_idx > N_C) rp_idx = N_C;
  int rpl = rowptr_c[rp_idx];
  const uint32* xp = (const uint32*)xth_a;

#pragma unroll 1
  for (int t = 0; t < 16; ++t) {
    int s = __shfl(rpl, 2 * t + half, 64);
    int e = __shfl(rpl, 2 * t + half + 1, 64);
    float a0 = 0.f, a1 = 0.f;
    int j = s;
    for (; j + 4 <= e; j += 4) {
      int c0 = col_tc[j], c1 = col_tc[j + 1], c2 = col_tc[j + 2], c3 = col_tc[j + 3];
      uint32 v0 = xp[(size_t)c0 * 32 + d];
      uint32 v1 = xp[(size_t)c1 * 32 + d];
      uint32 v2 = xp[(size_t)c2 * 32 + d];
      uint32 v3 = xp[(size_t)c3 * 32 + d];
      a0 += __uint_as_float(v0 << 16); a1 += __uint_as_float(v0 & 0xffff0000u);
      a0 += __uint_as_float(v1 << 16); a1 += __uint_as_float(v1 & 0xffff0000u);
      a0 += __uint_as_float(v2 << 16); a1 += __uint_as_float(v2 & 0xffff0000u);
      a0 += __uint_as_float(v3 << 16); a1 += __uint_as_float(v3 & 0xffff0000u);
    }
    for (; j < e; ++j) {
      uint32 v = xp[(size_t)col_tc[j] * 32 + d];
      a0 += __uint_as_float(v << 16); a1 += __uint_as_float(v & 0xffff0000u);
    }
    int deg = e - s;
    float inv = (deg > 0) ? (1.0f / (float)deg) : 0.f;
    uint32 packed = (uint32)f2bf(a0 * inv) | ((uint32)f2bf(a1 * inv) << 16);
    meanp[w * 32 + 2 * t + half][d] = packed;
  }
  __syncthreads();

  // MFMA combine: xnew = relu(M@Wl + X@Wr + bl) + X
  int lm = l & 15, lk = l >> 4;
  int base = bbase + w * 32;
  int r0 = base + lm;      if (r0 >= N_C) r0 = N_C - 1;
  int r1 = base + 16 + lm; if (r1 >= N_C) r1 = N_C - 1;
  const unsigned short* x0 = xch_a + (size_t)r0 * 64 + lk * 8;
  const unsigned short* x1 = xch_a + (size_t)r1 * 64 + lk * 8;
  const __bf16* wl = WlT + (size_t)lm * 64 + lk * 8;
  const __bf16* wr = WrT + (size_t)lm * 64 + lk * 8;

  f32x4 acc0[4] = {{0,0,0,0},{0,0,0,0},{0,0,0,0},{0,0,0,0}};
  f32x4 acc1[4] = {{0,0,0,0},{0,0,0,0},{0,0,0,0},{0,0,0,0}};

#pragma unroll
  for (int ks = 0; ks < 64; ks += 32) {
    bf16x8 am0 = *(const bf16x8*)&meanp[w * 32 + lm][lk * 4 + (ks >> 1)];
    bf16x8 am1 = *(const bf16x8*)&meanp[w * 32 + 16 + lm][lk * 4 + (ks >> 1)];
    bf16x8 ax0 = *(const bf16x8*)(x0 + ks);
    bf16x8 ax1 = *(const bf16x8*)(x1 + ks);
#pragma unroll
    for (int fn = 0; fn < 4; ++fn) {
      bf16x8 bl_v = *(const bf16x8*)(wl + (size_t)fn * 16 * 64 + ks);
      bf16x8 br_v = *(const bf16x8*)(wr + (size_t)fn * 16 * 64 + ks);
      acc0[fn] = __builtin_amdgcn_mfma_f32_16x16x32_bf16(am0, bl_v, acc0[fn], 0, 0, 0);
      acc1[fn] = __builtin_amdgcn_mfma_f32_16x16x32_bf16(am1, bl_v, acc1[fn], 0, 0, 0);
      acc0[fn] = __builtin_amdgcn_mfma_f32_16x16x32_bf16(ax0, br_v, acc0[fn], 0, 0, 0);
      acc1[fn] = __builtin_amdgcn_mfma_f32_16x16x32_bf16(ax1, br_v, acc1[fn], 0, 0, 0);
    }
  }

#pragma unroll
  for (int fn = 0; fn < 4; ++fn) {
    int col = fn * 16 + lm;
    float bb = bl_c[col];
#pragma unroll
    for (int reg = 0; reg < 4; ++reg) {
      int row = base + lk * 4 + reg;
      if (row < N_C) {
        float xv = xc_a[(size_t)row * 64 + col];
        float o = fmaxf(acc0[fn][reg] + bb, 0.f) + xv;
        xc_n[(size_t)row * 64 + col] = o;
        xch_n[(size_t)row * 64 + col] = f2bf(o);
      }
      row = base + 16 + lk * 4 + reg;
      if (row < N_C) {
        float xv = xc_a[(size_t)row * 64 + col];
        float o = fmaxf(acc1[fn][reg] + bb, 0.f) + xv;
        xc_n[(size_t)row * 64 + col] = o;
        xch_n[(size_t)row * 64 + col] = f2bf(o);
      }
    }
  }
}

// ---------------- head: out[r] = relu(xc[r] @ Wo1 + bo1) @ Wo2 + bo2
__global__ __launch_bounds__(256) void head_kernel(
    const float* __restrict__ xc, const float* __restrict__ Wo1,
    const float* __restrict__ bo1, const float* __restrict__ Wo2,
    const float* __restrict__ bo2, float* __restrict__ out, int n)
{
  int lane = threadIdx.x & 63;
  int wid = blockIdx.x * (blockDim.x >> 6) + (threadIdx.x >> 6);
  if (wid >= n) return;
  float xv = xc[(size_t)wid * 64 + lane];
  float h = (lane < H2) ? bo1[lane] : 0.f;
  const float* wcol = Wo1 + ((lane < H2) ? lane : 0);
#pragma unroll 8
  for (int k = 0; k < 64; ++k) {
    float xk = __uint_as_float(__builtin_amdgcn_readlane(__float_as_uint(xv), k));
    h = fmaf(xk, wcol[k * H2], h);
  }
  float v = (lane < H2) ? fmaxf(h, 0.f) * Wo2[lane] : 0.f;
#pragma unroll
  for (int off = 32; off > 0; off >>= 1) v += __shfl_down(v, off, 64);
  if (lane == 0) out[wid] = v + bo2[0];
}

extern "C" void kernel_launch(void* const* d_in, const int* in_sizes, int n_in,
                              void* d_out, int out_size, void* d_ws, size_t ws_size,
                              hipStream_t stream)
{
  const float* x_comp = (const float*)d_in[0];
  const float* x_tgt  = (const float*)d_in[1];
  const int*   src_ct = (const int*)d_in[2];
  const int*   dst_ct = (const int*)d_in[3];
  const int*   src_tc = (const int*)d_in[4];
  const int*   dst_tc = (const int*)d_in[5];
  const float* Wc    = (const float*)d_in[6];
  const float* bc    = (const float*)d_in[7];
  const float* Wt    = (const float*)d_in[8];
  const float* bt    = (const float*)d_in[9];
  const float* Wl_ct = (const float*)d_in[10];
  const float* bl_ct = (const float*)d_in[11];
  const float* Wr_ct = (const float*)d_in[12];
  const float* Wl_tc = (const float*)d_in[13];
  const float* bl_tc = (const float*)d_in[14];
  const float* Wr_tc = (const float*)d_in[15];
  const float* Wo1   = (const float*)d_in[16];
  const float* bo1   = (const float*)d_in[17];
  const float* Wo2   = (const float*)d_in[18];
  const float* bo2   = (const float*)d_in[19];
  float* out = (float*)d_out;

  char* p = (char*)d_ws;
  auto alloc = [&](size_t bytes) {
    char* q = p;
    p += (bytes + 255) & ~(size_t)255;
    return q;
  };
  float* xc   = (float*)alloc((size_t)N_C * H * 4);
  float* xt   = (float*)alloc((size_t)N_T * H * 4);
  float* xc_b = (float*)alloc((size_t)N_C * H * 4);
  float* xt_b = (float*)alloc((size_t)N_T * H * 4);
  unsigned short* xch   = (unsigned short*)alloc((size_t)N_C * H * 2);
  unsigned short* xth   = (unsigned short*)alloc((size_t)N_T * H * 2);
  unsigned short* xch_b = (unsigned short*)alloc((size_t)N_C * H * 2);
  unsigned short* xth_b = (unsigned short*)alloc((size_t)N_T * H * 2);
  __bf16* WcT = (__bf16*)alloc((size_t)D_C * H * 2);
  __bf16* WtT = (__bf16*)alloc((size_t)D_T * H * 2);
  __bf16* WsT = (__bf16*)alloc((size_t)6 * H * H * 2);
  int*   cnt_t     = (int*)alloc((size_t)N_T * 4);
  int*   cnt_c     = (int*)alloc((size_t)N_C * 4);
  int*   rowptr_t  = (int*)alloc((size_t)(N_T + 1) * 4);
  int*   rowptr_c  = (int*)alloc((size_t)(N_C + 1) * 4);
  int*   fillptr_t = (int*)alloc((size_t)N_T * 4);
  int*   fillptr_c = (int*)alloc((size_t)N_C * 4);
  int*   col_ct    = (int*)alloc((size_t)E_EDGES * 4);
  int*   col_tc    = (int*)alloc((size_t)E_EDGES * 4);
  int*   bsum      = (int*)alloc(256 * 4);

  // node 1: weight prep + zero counters
  const int PREP_TOTAL = (N_T + N_C) + D_C * 64 + D_T * 64 + 6 * 4096;
  prep_kernel<<<dim3((PREP_TOTAL + 255) / 256), dim3(256), 0, stream>>>(
      Wc, Wt, Wl_tc, Wr_tc, WcT, WtT, WsT, cnt_t, cnt_c);

  // node 2: both dense input projections
  proj_kernel<<<dim3(NBC + NBT), dim3(256), 0, stream>>>(
      x_comp, WcT, bc, xc, xch, x_tgt, WtT, bt, xt, xth);

  // node 3: both histograms
  hist_kernel<<<dim3(128 + 2048), dim3(256), 0, stream>>>(dst_ct, cnt_t, dst_tc, cnt_c);

  // nodes 4-5: scans (compound 2-phase, target single-block inside scanA)
  scanA_kernel<<<dim3(99), dim3(256), 0, stream>>>(cnt_c, rowptr_c, bsum, cnt_t, rowptr_t, fillptr_t);
  scanB_kernel<<<dim3(98), dim3(256), 0, stream>>>(bsum, rowptr_c, fillptr_c);

  // node 6: both CSR fills
  fill_kernel<<<dim3(4096), dim3(256), 0, stream>>>(
      src_ct, dst_ct, fillptr_t, col_ct, src_tc, dst_tc, fillptr_c, col_tc);

  // nodes 7-9: one fused node per layer
  float* xc_a = xc; float* xt_a = xt;
  float* xc_n = xc_b; float* xt_n = xt_b;
  unsigned short* xch_a = xch; unsigned short* xth_a = xth;
  unsigned short* xch_n = xch_b; unsigned short* xth_n = xth_b;
  for (int l = 0; l < NL; ++l) {
    layer_kernel<<<dim3(N_T + NBC), dim3(256), 0, stream>>>(
        xch_a, xt_a, rowptr_t, col_ct,
        Wl_ct + (size_t)l * H * H, bl_ct + (size_t)l * H, Wr_ct + (size_t)l * H * H,
        xt_n, xth_n,
        xth_a, rowptr_c, col_tc,
        WsT + (size_t)l * H * H, WsT + (size_t)(3 + l) * H * H,
        bl_tc + (size_t)l * H, xc_a, xc_n, xch_n);
    float* t;
    t = xc_a; xc_a = xc_n; xc_n = t;
    t = xt_a; xt_a = xt_n; xt_n = t;
    unsigned short* th;
    th = xch_a; xch_a = xch_n; xch_n = th;
    th = xth_a; xth_a = xth_n; xth_n = th;
  }

  // node 10: output head
  head_kernel<<<dim3((N_C + 3) / 4), dim3(256), 0, stream>>>(xc_a, Wo1, bo1, Wo2, bo2, out, N_C);
}

// Round 2
// 780.701 us; speedup vs baseline: 1.3392x; 1.3392x over previous
//
#include <hip/hip_runtime.h>

typedef unsigned int uint32;
typedef __bf16 bf16x8 __attribute__((ext_vector_type(8)));
typedef float f32x4 __attribute__((ext_vector_type(4)));

constexpr int N_C = 100000, N_T = 5000, E_EDGES = 2000000;
constexpr int D_C = 1024, D_T = 1280, H = 64, H2 = 32, NL = 3;
constexpr int NBC = (N_C + 127) / 128;   // 782 MFMA blocks for compounds
constexpr int NBT = (N_T + 127) / 128;   // 40

// ---- CSR build (two-level counting sort, zero atomic-with-return) ----
constexpr int CCH = 200;                  // chunks per graph
constexpr int CHE = E_EDGES / CCH;        // 10000 edges per chunk (exact)
constexpr int SH_T = 4,  FB_T = 16;       // target: bucket = dst>>4, 16 fine bins
constexpr int SH_C = 8,  FB_C = 256;      // compound: bucket = dst>>8, 256 fine bins
constexpr int NB_T_B = (N_T + FB_T - 1) / FB_T;   // 313 buckets
constexpr int NB_C_B = (N_C + FB_C - 1) / FB_C;   // 391 buckets
constexpr int NB_TOT = NB_T_B + NB_C_B;           // 704

__device__ inline unsigned short f2bf(float f) {
  uint32 u = __float_as_uint(f);
  u += 0x7fffu + ((u >> 16) & 1u);          // round-to-nearest-even
  return (unsigned short)(u >> 16);
}

// ---------------- prep: weight transposes + zero bucket totals (1 node)
__global__ __launch_bounds__(256) void prep_kernel(
    const float* __restrict__ Wc, const float* __restrict__ Wt,
    const float* __restrict__ Wl, const float* __restrict__ Wr,
    __bf16* __restrict__ WcT, __bf16* __restrict__ WtT, __bf16* __restrict__ WsT,
    int* __restrict__ T)
{
  int t = blockIdx.x * 256 + threadIdx.x;
  const int Z = NB_TOT;
  const int A = D_C * 64;
  const int B = D_T * 64;
  const int S = 6 * 64 * 64;
  if (t < Z) { T[t] = 0; return; }
  t -= Z;
  if (t < A) { int n = t & 63, k = t >> 6; WcT[(size_t)n * D_C + k] = (__bf16)Wc[(size_t)k * 64 + n]; return; }
  t -= A;
  if (t < B) { int n = t & 63, k = t >> 6; WtT[(size_t)n * D_T + k] = (__bf16)Wt[(size_t)k * 64 + n]; return; }
  t -= B;
  if (t < S) {
    int i = t >> 12;
    int r = t & 4095; int n = r & 63, k = r >> 6;
    const float* src = (i < 3) ? (Wl + (size_t)i * 4096) : (Wr + (size_t)(i - 3) * 4096);
    WsT[(size_t)i * 4096 + (size_t)n * 64 + k] = (__bf16)src[(size_t)k * 64 + n];
  }
}

// ---------------- MFMA projection body: y = relu(x @ W + b)
template<int K>
__device__ __forceinline__ void projM_body(
    const float* __restrict__ x, const __bf16* __restrict__ WT,
    const float* __restrict__ b, float* __restrict__ y,
    unsigned short* __restrict__ yh, int n, int bidx)
{
  int w = threadIdx.x >> 6, l = threadIdx.x & 63;
  int lm = l & 15, lk = l >> 4;
  int base = bidx * 128 + w * 32;
  int r0 = base + lm;      if (r0 >= n) r0 = n - 1;
  int r1 = base + 16 + lm; if (r1 >= n) r1 = n - 1;
  const float* xp0 = x + (size_t)r0 * K + lk * 8;
  const float* xp1 = x + (size_t)r1 * K + lk * 8;
  const __bf16* wp = WT + (size_t)lm * K + lk * 8;

  f32x4 acc0[4] = {{0,0,0,0},{0,0,0,0},{0,0,0,0},{0,0,0,0}};
  f32x4 acc1[4] = {{0,0,0,0},{0,0,0,0},{0,0,0,0},{0,0,0,0}};

  float4 p00 = *(const float4*)(xp0);
  float4 p01 = *(const float4*)(xp0 + 4);
  float4 p10 = *(const float4*)(xp1);
  float4 p11 = *(const float4*)(xp1 + 4);

  for (int k0 = 0; k0 < K; k0 += 32) {
    bf16x8 a0, a1;
    a0[0]=(__bf16)p00.x; a0[1]=(__bf16)p00.y; a0[2]=(__bf16)p00.z; a0[3]=(__bf16)p00.w;
    a0[4]=(__bf16)p01.x; a0[5]=(__bf16)p01.y; a0[6]=(__bf16)p01.z; a0[7]=(__bf16)p01.w;
    a1[0]=(__bf16)p10.x; a1[1]=(__bf16)p10.y; a1[2]=(__bf16)p10.z; a1[3]=(__bf16)p10.w;
    a1[4]=(__bf16)p11.x; a1[5]=(__bf16)p11.y; a1[6]=(__bf16)p11.z; a1[7]=(__bf16)p11.w;
    if (k0 + 32 < K) {
      p00 = *(const float4*)(xp0 + k0 + 32);
      p01 = *(const float4*)(xp0 + k0 + 36);
      p10 = *(const float4*)(xp1 + k0 + 32);
      p11 = *(const float4*)(xp1 + k0 + 36);
    }
#pragma unroll
    for (int fn = 0; fn < 4; ++fn) {
      bf16x8 bv = *(const bf16x8*)(wp + (size_t)fn * 16 * K + k0);
      acc0[fn] = __builtin_amdgcn_mfma_f32_16x16x32_bf16(a0, bv, acc0[fn], 0, 0, 0);
      acc1[fn] = __builtin_amdgcn_mfma_f32_16x16x32_bf16(a1, bv, acc1[fn], 0, 0, 0);
    }
  }

#pragma unroll
  for (int fn = 0; fn < 4; ++fn) {
    int col = fn * 16 + lm;
    float bb = b[col];
#pragma unroll
    for (int reg = 0; reg < 4; ++reg) {
      int row = base + lk * 4 + reg;
      if (row < n) {
        float o = fmaxf(acc0[fn][reg] + bb, 0.f);
        y[(size_t)row * 64 + col] = o;
        yh[(size_t)row * 64 + col] = f2bf(o);
      }
      row = base + 16 + lk * 4 + reg;
      if (row < n) {
        float o = fmaxf(acc1[fn][reg] + bb, 0.f);
        y[(size_t)row * 64 + col] = o;
        yh[(size_t)row * 64 + col] = f2bf(o);
      }
    }
  }
}

__global__ __launch_bounds__(256) void proj_kernel(
    const float* __restrict__ x_comp, const __bf16* __restrict__ WcT,
    const float* __restrict__ bc, float* __restrict__ xc, unsigned short* __restrict__ xch,
    const float* __restrict__ x_tgt, const __bf16* __restrict__ WtT,
    const float* __restrict__ bt, float* __restrict__ xt, unsigned short* __restrict__ xth)
{
  if (blockIdx.x < NBC) projM_body<D_C>(x_comp, WcT, bc, xc, xch, N_C, blockIdx.x);
  else                  projM_body<D_T>(x_tgt, WtT, bt, xt, xth, N_T, blockIdx.x - NBC);
}

// ---------------- csr1: per-chunk coarse-bucket histograms (LDS), no returns needed
__global__ __launch_bounds__(256) void csr1_kernel(
    const int* __restrict__ dst_ct, const int* __restrict__ dst_tc,
    int* __restrict__ h1, int* __restrict__ T)
{
  __shared__ int hist[NB_C_B];
  int graph = (blockIdx.x >= CCH) ? 1 : 0;
  int chunk = graph ? (blockIdx.x - CCH) : blockIdx.x;
  const int* dst = graph ? dst_tc : dst_ct;
  int NB = graph ? NB_C_B : NB_T_B;
  int SH = graph ? SH_C : SH_T;
  for (int i = threadIdx.x; i < NB; i += 256) hist[i] = 0;
  __syncthreads();
  int e0 = chunk * CHE;
  for (int i = threadIdx.x; i < CHE; i += 256)
    atomicAdd(&hist[dst[e0 + i] >> SH], 1);
  __syncthreads();
  int* h1g = h1 + (graph ? (size_t)NB_T_B * CCH : 0);
  int* Tg  = T + (graph ? NB_T_B : 0);
  for (int i = threadIdx.x; i < NB; i += 256) {
    int v = hist[i];
    h1g[(size_t)i * CCH + chunk] = v;
    if (v) atomicAdd(&Tg[i], v);       // fire-and-forget, ~110K total
  }
}

// ---------------- csr2: per-bucket bases (redundant scan of T) + chunk-prefix of h1 row
__global__ __launch_bounds__(256) void csr2_kernel(
    const int* __restrict__ h1, const int* __restrict__ T, int* __restrict__ b1)
{
  __shared__ int sh[256];
  __shared__ int loc2[512];
  int b = blockIdx.x;                      // 0..703
  int graph = (b >= NB_T_B) ? 1 : 0;
  int nb = graph ? NB_C_B : NB_T_B;
  int base = graph ? NB_T_B : 0;
  int bl = b - base;
  int tid = threadIdx.x;
  // exclusive scan of this graph's bucket totals (<=391, 2 per thread)
  int v0 = (2 * tid     < nb) ? T[base + 2 * tid]     : 0;
  int v1 = (2 * tid + 1 < nb) ? T[base + 2 * tid + 1] : 0;
  int t = v0 + v1;
  sh[tid] = t;
  __syncthreads();
  for (int off = 1; off < 256; off <<= 1) {
    int xv = (tid >= off) ? sh[tid - off] : 0;
    __syncthreads(); sh[tid] += xv; __syncthreads();
  }
  int excl = sh[tid] - t;
  loc2[2 * tid] = excl;
  loc2[2 * tid + 1] = excl + v0;
  __syncthreads();
  int B = loc2[bl];                        // bucket base within this graph's edge space
  // exclusive chunk-prefix of own h1 row (CCH entries)
  const int* row = h1 + (graph ? (size_t)NB_T_B * CCH : 0) + (size_t)bl * CCH;
  int hv = (tid < CCH) ? row[tid] : 0;
  sh[tid] = hv;
  __syncthreads();
  for (int off = 1; off < 256; off <<= 1) {
    int xv = (tid >= off) ? sh[tid - off] : 0;
    __syncthreads(); sh[tid] += xv; __syncthreads();
  }
  int e2 = sh[tid] - hv;
  if (tid < CCH) {
    int* b1g = b1 + (graph ? (size_t)NB_T_B * CCH : 0) + (size_t)bl * CCH;
    b1g[tid] = B + e2;
  }
}

// ---------------- csr3: scatter edges into bucket-major temp (LDS cursors, packed u32)
__global__ __launch_bounds__(256) void csr3_kernel(
    const int* __restrict__ src_ct, const int* __restrict__ dst_ct,
    const int* __restrict__ src_tc, const int* __restrict__ dst_tc,
    const int* __restrict__ b1, uint32* __restrict__ packT_t, uint32* __restrict__ packT_c)
{
  __shared__ int cur[NB_C_B];
  int graph = (blockIdx.x >= CCH) ? 1 : 0;
  int chunk = graph ? (blockIdx.x - CCH) : blockIdx.x;
  const int* dst = graph ? dst_tc : dst_ct;
  const int* src = graph ? src_tc : src_ct;
  uint32* packT = graph ? packT_c : packT_t;
  int NB = graph ? NB_C_B : NB_T_B;
  int SH = graph ? SH_C : SH_T;
  int SB = graph ? 13 : 17;                // fine<<SB | src  (21 bits total both ways)
  uint32 FM = graph ? 255u : 15u;
  const int* b1g = b1 + (graph ? (size_t)NB_T_B * CCH : 0);
  for (int i = threadIdx.x; i < NB; i += 256) cur[i] = b1g[(size_t)i * CCH + chunk];
  __syncthreads();
  int e0 = chunk * CHE;
  for (int i = threadIdx.x; i < CHE; i += 256) {
    int d = dst[e0 + i], s = src[e0 + i];
    int p = atomicAdd(&cur[d >> SH], 1);   // LDS atomic — cheap
    packT[p] = (((uint32)d & FM) << SB) | (uint32)s;
  }
}

// ---------------- csr4: per-bucket fine counting sort -> rowptr + col (window-local writes)
__global__ __launch_bounds__(256) void csr4_kernel(
    const int* __restrict__ b1, const uint32* __restrict__ packT_t,
    const uint32* __restrict__ packT_c,
    int* __restrict__ rowptr_t, int* __restrict__ col_ct,
    int* __restrict__ rowptr_c, int* __restrict__ col_tc)
{
  __shared__ int hist[FB_C];
  __shared__ int exc[256];
  int b = blockIdx.x;
  int graph = (b >= NB_T_B) ? 1 : 0;
  int bl = graph ? (b - NB_T_B) : b;
  int nb = graph ? NB_C_B : NB_T_B;
  int FB = graph ? FB_C : FB_T;
  int SB = graph ? 13 : 17;
  uint32 SM = graph ? 0x1FFFu : 0x1FFFFu;
  int N  = graph ? N_C : N_T;
  const uint32* packT = graph ? packT_c : packT_t;
  int* rowptr = graph ? rowptr_c : rowptr_t;
  int* col    = graph ? col_tc : col_ct;
  const int* b1g = b1 + (graph ? (size_t)NB_T_B * CCH : 0);
  int seg0 = b1g[(size_t)bl * CCH];
  int seg1 = (bl + 1 < nb) ? b1g[(size_t)(bl + 1) * CCH] : E_EDGES;
  int tid = threadIdx.x;
  if (tid < FB) hist[tid] = 0;
  __syncthreads();
  for (int i = seg0 + tid; i < seg1; i += 256)
    atomicAdd(&hist[packT[i] >> SB], 1);
  __syncthreads();
  int hv = (tid < FB) ? hist[tid] : 0;
  exc[tid] = hv;
  __syncthreads();
  for (int off = 1; off < 256; off <<= 1) {
    int xv = (tid >= off) ? exc[tid - off] : 0;
    __syncthreads(); exc[tid] += xv; __syncthreads();
  }
  int excl = exc[tid] - hv;                // exclusive fine prefix (valid tid<FB)
  __syncthreads();
  if (tid < FB) {
    int gbin = bl * FB + tid;
    if (gbin <= N) rowptr[gbin] = seg0 + excl;   // covers rowptr[N]=E in last bucket
    hist[tid] = seg0 + excl;                     // becomes cursor
  }
  __syncthreads();
  for (int i = seg0 + tid; i < seg1; i += 256) {
    uint32 pk = packT[i];
    int p = atomicAdd(&hist[pk >> SB], 1);       // LDS atomic
    col[p] = (int)(pk & SM);                     // write inside ~40KB window
  }
}

// ---------------- one node per layer: target SAGE (blocks [0,N_T)) + fused compound agg+MFMA
__global__ __launch_bounds__(256) void layer_kernel(
    // target side
    const unsigned short* __restrict__ xch_a, const float* __restrict__ xt_a,
    const int* __restrict__ rowptr_t, const int* __restrict__ col_ct,
    const float* __restrict__ Wl_t, const float* __restrict__ bl_t, const float* __restrict__ Wr_t,
    float* __restrict__ xt_n, unsigned short* __restrict__ xth_n,
    // compound side
    const unsigned short* __restrict__ xth_a, const int* __restrict__ rowptr_c,
    const int* __restrict__ col_tc,
    const __bf16* __restrict__ WlT, const __bf16* __restrict__ WrT,
    const float* __restrict__ bl_c, const float* __restrict__ xc_a,
    float* __restrict__ xc_n, unsigned short* __restrict__ xch_n)
{
  __shared__ __align__(16) uint32 meanp[128][36];   // packed bf16 pairs, padded row
  __shared__ __align__(16) float part[4][64];
  __shared__ __align__(16) float opart[4][64];

  int l = threadIdx.x & 63, w = threadIdx.x >> 6;
  int d = l & 31, half = l >> 5;

  if (blockIdx.x < N_T) {
    // -------- target-side SAGE: one block per row; wave quarters, lane-halves by edge parity
    int r = blockIdx.x;
    int start = rowptr_t[r], end = rowptr_t[r + 1];
    int deg = end - start;
    int quarter = (deg + 3) >> 2;
    int js = start + w * quarter;
    int je = js + quarter; if (je > end) je = end;
    const uint32* xp = (const uint32*)xch_a;
    float a0 = 0.f, a1 = 0.f;
    int j = js + half;
    for (; j + 6 < je; j += 8) {
      int c0 = col_ct[j], c1 = col_ct[j + 2], c2 = col_ct[j + 4], c3 = col_ct[j + 6];
      uint32 v0 = xp[(size_t)c0 * 32 + d];
      uint32 v1 = xp[(size_t)c1 * 32 + d];
      uint32 v2 = xp[(size_t)c2 * 32 + d];
      uint32 v3 = xp[(size_t)c3 * 32 + d];
      a0 += __uint_as_float(v0 << 16); a1 += __uint_as_float(v0 & 0xffff0000u);
      a0 += __uint_as_float(v1 << 16); a1 += __uint_as_float(v1 & 0xffff0000u);
      a0 += __uint_as_float(v2 << 16); a1 += __uint_as_float(v2 & 0xffff0000u);
      a0 += __uint_as_float(v3 << 16); a1 += __uint_as_float(v3 & 0xffff0000u);
    }
    for (; j < je; j += 2) {
      uint32 v = xp[(size_t)col_ct[j] * 32 + d];
      a0 += __uint_as_float(v << 16); a1 += __uint_as_float(v & 0xffff0000u);
    }
    a0 += __shfl_xor(a0, 32, 64);
    a1 += __shfl_xor(a1, 32, 64);
    if (half == 0) *(float2*)&part[w][2 * d] = make_float2(a0, a1);
    __syncthreads();
    float m = (part[0][l] + part[1][l] + part[2][l] + part[3][l])
              * ((deg > 0) ? (1.0f / (float)deg) : 0.f);
    float xv = xt_a[(size_t)r * 64 + l];
    float o = 0.f;
    int k0 = w * 16;
#pragma unroll
    for (int kk = 0; kk < 16; ++kk) {
      int k = k0 + kk;
      float mk = __uint_as_float(__builtin_amdgcn_readlane(__float_as_uint(m), k));
      float xk = __uint_as_float(__builtin_amdgcn_readlane(__float_as_uint(xv), k));
      o = fmaf(mk, Wl_t[k * 64 + l], o);
      o = fmaf(xk, Wr_t[k * 64 + l], o);
    }
    opart[w][l] = o;
    __syncthreads();
    if (w == 0) {
      float oo = opart[0][l] + opart[1][l] + opart[2][l] + opart[3][l] + bl_t[l];
      float res = fmaxf(oo, 0.f) + xv;
      xt_n[(size_t)r * 64 + l] = res;
      xth_n[(size_t)r * 64 + l] = f2bf(res);
    }
    return;
  }

  // -------- compound side: aggregate 32 rows/wave into LDS, then MFMA combine
  int bblk = blockIdx.x - N_T;
  int bbase = bblk * 128;

  int rp_idx = bbase + w * 32 + ((l <= 32) ? l : 32);
  if (rp_idx > N_C) rp_idx = N_C;
  int rpl = rowptr_c[rp_idx];
  const uint32* xp = (const uint32*)xth_a;

#pragma unroll 1
  for (int t = 0; t < 16; ++t) {
    int s = __shfl(rpl, 2 * t + half, 64);
    int e = __shfl(rpl, 2 * t + half + 1, 64);
    float a0 = 0.f, a1 = 0.f;
    int j = s;
    for (; j + 4 <= e; j += 4) {
      int c0 = col_tc[j], c1 = col_tc[j + 1], c2 = col_tc[j + 2], c3 = col_tc[j + 3];
      uint32 v0 = xp[(size_t)c0 * 32 + d];
      uint32 v1 = xp[(size_t)c1 * 32 + d];
      uint32 v2 = xp[(size_t)c2 * 32 + d];
      uint32 v3 = xp[(size_t)c3 * 32 + d];
      a0 += __uint_as_float(v0 << 16); a1 += __uint_as_float(v0 & 0xffff0000u);
      a0 += __uint_as_float(v1 << 16); a1 += __uint_as_float(v1 & 0xffff0000u);
      a0 += __uint_as_float(v2 << 16); a1 += __uint_as_float(v2 & 0xffff0000u);
      a0 += __uint_as_float(v3 << 16); a1 += __uint_as_float(v3 & 0xffff0000u);
    }
    for (; j < e; ++j) {
      uint32 v = xp[(size_t)col_tc[j] * 32 + d];
      a0 += __uint_as_float(v << 16); a1 += __uint_as_float(v & 0xffff0000u);
    }
    int deg = e - s;
    float inv = (deg > 0) ? (1.0f / (float)deg) : 0.f;
    uint32 packed = (uint32)f2bf(a0 * inv) | ((uint32)f2bf(a1 * inv) << 16);
    meanp[w * 32 + 2 * t + half][d] = packed;
  }
  __syncthreads();

  int lm = l & 15, lk = l >> 4;
  int base = bbase + w * 32;
  int r0 = base + lm;      if (r0 >= N_C) r0 = N_C - 1;
  int r1 = base + 16 + lm; if (r1 >= N_C) r1 = N_C - 1;
  const unsigned short* x0 = xch_a + (size_t)r0 * 64 + lk * 8;
  const unsigned short* x1 = xch_a + (size_t)r1 * 64 + lk * 8;
  const __bf16* wl = WlT + (size_t)lm * 64 + lk * 8;
  const __bf16* wr = WrT + (size_t)lm * 64 + lk * 8;

  f32x4 acc0[4] = {{0,0,0,0},{0,0,0,0},{0,0,0,0},{0,0,0,0}};
  f32x4 acc1[4] = {{0,0,0,0},{0,0,0,0},{0,0,0,0},{0,0,0,0}};

#pragma unroll
  for (int ks = 0; ks < 64; ks += 32) {
    bf16x8 am0 = *(const bf16x8*)&meanp[w * 32 + lm][lk * 4 + (ks >> 1)];
    bf16x8 am1 = *(const bf16x8*)&meanp[w * 32 + 16 + lm][lk * 4 + (ks >> 1)];
    bf16x8 ax0 = *(const bf16x8*)(x0 + ks);
    bf16x8 ax1 = *(const bf16x8*)(x1 + ks);
#pragma unroll
    for (int fn = 0; fn < 4; ++fn) {
      bf16x8 bl_v = *(const bf16x8*)(wl + (size_t)fn * 16 * 64 + ks);
      bf16x8 br_v = *(const bf16x8*)(wr + (size_t)fn * 16 * 64 + ks);
      acc0[fn] = __builtin_amdgcn_mfma_f32_16x16x32_bf16(am0, bl_v, acc0[fn], 0, 0, 0);
      acc1[fn] = __builtin_amdgcn_mfma_f32_16x16x32_bf16(am1, bl_v, acc1[fn], 0, 0, 0);
      acc0[fn] = __builtin_amdgcn_mfma_f32_16x16x32_bf16(ax0, br_v, acc0[fn], 0, 0, 0);
      acc1[fn] = __builtin_amdgcn_mfma_f32_16x16x32_bf16(ax1, br_v, acc1[fn], 0, 0, 0);
    }
  }

#pragma unroll
  for (int fn = 0; fn < 4; ++fn) {
    int col = fn * 16 + lm;
    float bb = bl_c[col];
#pragma unroll
    for (int reg = 0; reg < 4; ++reg) {
      int row = base + lk * 4 + reg;
      if (row < N_C) {
        float xv = xc_a[(size_t)row * 64 + col];
        float o = fmaxf(acc0[fn][reg] + bb, 0.f) + xv;
        xc_n[(size_t)row * 64 + col] = o;
        xch_n[(size_t)row * 64 + col] = f2bf(o);
      }
      row = base + 16 + lk * 4 + reg;
      if (row < N_C) {
        float xv = xc_a[(size_t)row * 64 + col];
        float o = fmaxf(acc1[fn][reg] + bb, 0.f) + xv;
        xc_n[(size_t)row * 64 + col] = o;
        xch_n[(size_t)row * 64 + col] = f2bf(o);
      }
    }
  }
}

// ---------------- head: out[r] = relu(xc[r] @ Wo1 + bo1) @ Wo2 + bo2
__global__ __launch_bounds__(256) void head_kernel(
    const float* __restrict__ xc, const float* __restrict__ Wo1,
    const float* __restrict__ bo1, const float* __restrict__ Wo2,
    const float* __restrict__ bo2, float* __restrict__ out, int n)
{
  int lane = threadIdx.x & 63;
  int wid = blockIdx.x * (blockDim.x >> 6) + (threadIdx.x >> 6);
  if (wid >= n) return;
  float xv = xc[(size_t)wid * 64 + lane];
  float h = (lane < H2) ? bo1[lane] : 0.f;
  const float* wcol = Wo1 + ((lane < H2) ? lane : 0);
#pragma unroll 8
  for (int k = 0; k < 64; ++k) {
    float xk = __uint_as_float(__builtin_amdgcn_readlane(__float_as_uint(xv), k));
    h = fmaf(xk, wcol[k * H2], h);
  }
  float v = (lane < H2) ? fmaxf(h, 0.f) * Wo2[lane] : 0.f;
#pragma unroll
  for (int off = 32; off > 0; off >>= 1) v += __shfl_down(v, off, 64);
  if (lane == 0) out[wid] = v + bo2[0];
}

extern "C" void kernel_launch(void* const* d_in, const int* in_sizes, int n_in,
                              void* d_out, int out_size, void* d_ws, size_t ws_size,
                              hipStream_t stream)
{
  const float* x_comp = (const float*)d_in[0];
  const float* x_tgt  = (const float*)d_in[1];
  const int*   src_ct = (const int*)d_in[2];
  const int*   dst_ct = (const int*)d_in[3];
  const int*   src_tc = (const int*)d_in[4];
  const int*   dst_tc = (const int*)d_in[5];
  const float* Wc    = (const float*)d_in[6];
  const float* bc    = (const float*)d_in[7];
  const float* Wt    = (const float*)d_in[8];
  const float* bt    = (const float*)d_in[9];
  const float* Wl_ct = (const float*)d_in[10];
  const float* bl_ct = (const float*)d_in[11];
  const float* Wr_ct = (const float*)d_in[12];
  const float* Wl_tc = (const float*)d_in[13];
  const float* bl_tc = (const float*)d_in[14];
  const float* Wr_tc = (const float*)d_in[15];
  const float* Wo1   = (const float*)d_in[16];
  const float* bo1   = (const float*)d_in[17];
  const float* Wo2   = (const float*)d_in[18];
  const float* bo2   = (const float*)d_in[19];
  float* out = (float*)d_out;

  char* p = (char*)d_ws;
  auto alloc = [&](size_t bytes) {
    char* q = p;
    p += (bytes + 255) & ~(size_t)255;
    return q;
  };
  float* xc   = (float*)alloc((size_t)N_C * H * 4);
  float* xt   = (float*)alloc((size_t)N_T * H * 4);
  float* xc_b = (float*)alloc((size_t)N_C * H * 4);
  float* xt_b = (float*)alloc((size_t)N_T * H * 4);
  unsigned short* xch   = (unsigned short*)alloc((size_t)N_C * H * 2);
  unsigned short* xth   = (unsigned short*)alloc((size_t)N_T * H * 2);
  unsigned short* xch_b = (unsigned short*)alloc((size_t)N_C * H * 2);
  unsigned short* xth_b = (unsigned short*)alloc((size_t)N_T * H * 2);
  __bf16* WcT = (__bf16*)alloc((size_t)D_C * H * 2);
  __bf16* WtT = (__bf16*)alloc((size_t)D_T * H * 2);
  __bf16* WsT = (__bf16*)alloc((size_t)6 * H * H * 2);
  int*    h1        = (int*)alloc((size_t)NB_TOT * CCH * 4);
  int*    b1        = (int*)alloc((size_t)NB_TOT * CCH * 4);
  int*    T         = (int*)alloc((size_t)NB_TOT * 4);
  uint32* packT_t   = (uint32*)alloc((size_t)E_EDGES * 4);
  uint32* packT_c   = (uint32*)alloc((size_t)E_EDGES * 4);
  int*    rowptr_t  = (int*)alloc((size_t)(N_T + 1) * 4);
  int*    rowptr_c  = (int*)alloc((size_t)(N_C + 1) * 4);
  int*    col_ct    = (int*)alloc((size_t)E_EDGES * 4);
  int*    col_tc    = (int*)alloc((size_t)E_EDGES * 4);

  // node 1: weight prep + zero bucket totals
  const int PREP_TOTAL = NB_TOT + D_C * 64 + D_T * 64 + 6 * 4096;
  prep_kernel<<<dim3((PREP_TOTAL + 255) / 256), dim3(256), 0, stream>>>(
      Wc, Wt, Wl_tc, Wr_tc, WcT, WtT, WsT, T);

  // node 2: both dense input projections
  proj_kernel<<<dim3(NBC + NBT), dim3(256), 0, stream>>>(
      x_comp, WcT, bc, xc, xch, x_tgt, WtT, bt, xt, xth);

  // nodes 3-6: CSR build via two-level counting sort (no global atomic-with-return)
  csr1_kernel<<<dim3(2 * CCH), dim3(256), 0, stream>>>(dst_ct, dst_tc, h1, T);
  csr2_kernel<<<dim3(NB_TOT), dim3(256), 0, stream>>>(h1, T, b1);
  csr3_kernel<<<dim3(2 * CCH), dim3(256), 0, stream>>>(
      src_ct, dst_ct, src_tc, dst_tc, b1, packT_t, packT_c);
  csr4_kernel<<<dim3(NB_TOT), dim3(256), 0, stream>>>(
      b1, packT_t, packT_c, rowptr_t, col_ct, rowptr_c, col_tc);

  // nodes 7-9: one fused node per layer
  float* xc_a = xc; float* xt_a = xt;
  float* xc_n = xc_b; float* xt_n = xt_b;
  unsigned short* xch_a = xch; unsigned short* xth_a = xth;
  unsigned short* xch_n = xch_b; unsigned short* xth_n = xth_b;
  for (int l = 0; l < NL; ++l) {
    layer_kernel<<<dim3(N_T + NBC), dim3(256), 0, stream>>>(
        xch_a, xt_a, rowptr_t, col_ct,
        Wl_ct + (size_t)l * H * H, bl_ct + (size_t)l * H, Wr_ct + (size_t)l * H * H,
        xt_n, xth_n,
        xth_a, rowptr_c, col_tc,
        WsT + (size_t)l * H * H, WsT + (size_t)(3 + l) * H * H,
        bl_tc + (size_t)l * H, xc_a, xc_n, xch_n);
    float* t;
    t = xc_a; xc_a = xc_n; xc_n = t;
    t = xt_a; xt_a = xt_n; xt_n = t;
    unsigned short* th;
    th = xch_a; xch_a = xch_n; xch_n = th;
    th = xth_a; xth_a = xth_n; xth_n = th;
  }

  // node 10: output head
  head_kernel<<<dim3((N_C + 3) / 4), dim3(256), 0, stream>>>(xc_a, Wo1, bo1, Wo2, bo2, out, N_C);
}